// Round 7
// baseline (461.187 us; speedup 1.0000x reference)
//
#include <hip/hip_runtime.h>
#include <hip/hip_bf16.h>
#include <cstdint>
#include <cstddef>

typedef __bf16 bf16;
typedef __bf16 bf16x8 __attribute__((ext_vector_type(8)));
typedef __bf16 bf16x4 __attribute__((ext_vector_type(4)));
typedef float f32x4 __attribute__((ext_vector_type(4)));

static constexpr int BATCH = 2;
static constexpr int SEQ = 2048;
static constexpr int DMODEL = 2048;
static constexpr int NH = 16;
static constexpr int HD = 128;
static constexpr int MROWS = BATCH * SEQ; // 4096

#define GLOBAL_AS(p) ((const __attribute__((address_space(1))) void*)(p))
#define LDS_AS(p)    ((__attribute__((address_space(3))) void*)(p))

// ---------------- fused fp32 -> bf16 convert (x, Wq, Wk, Wv, Wo in one launch) ----
// float4-group counts: x = 2,097,152 ; each W = 1,048,576 ; total 6,291,456.
__global__ void cvt5_kernel(const float* __restrict__ x,
                            const float* __restrict__ wq, const float* __restrict__ wk,
                            const float* __restrict__ wv, const float* __restrict__ wo,
                            bf16* __restrict__ dst) {
  const int i = blockIdx.x * blockDim.x + threadIdx.x;   // global float4 index
  const float* src;
  int local;
  if (i < 2097152) { src = x; local = i; }
  else {
    const int r = i - 2097152;
    const int w = r >> 20;            // 0..3 (block-uniform: 4096 blocks per weight)
    local = r & 1048575;
    src = (w == 0) ? wq : (w == 1) ? wk : (w == 2) ? wv : wo;
  }
  float4 f = reinterpret_cast<const float4*>(src)[local];
  bf16x4 o;
  o.x = (bf16)f.x; o.y = (bf16)f.y; o.z = (bf16)f.z; o.w = (bf16)f.w;
  reinterpret_cast<bf16x4*>(dst)[i] = o;
}

// ---------------- GEMM: C = A(MxK,row) * W(NxK,row)^T ----------------
// m97 structure + rotation swizzle (round 6: 0 bank conflicts, 1000 TF).
enum { MODE_QKV = 0, MODE_OUT = 1 };

template <int MODE>
__global__ __launch_bounds__(256, 4) void gemm_bt(
    const bf16* __restrict__ A, const bf16* __restrict__ W,
    bf16* __restrict__ Oq, bf16* __restrict__ Ok, bf16* __restrict__ Ov,
    float* __restrict__ Oout) {
  constexpr int Kd = DMODEL;
  __shared__ __align__(16) bf16 As[128][64];
  __shared__ __align__(16) bf16 Bs[128][64];
  const int n0 = blockIdx.x * 128;
  const int m0 = blockIdx.y * 128;
  const int tid = threadIdx.x;
  const int wave = tid >> 6;
  const int lane = tid & 63;
  const int quad = lane >> 4;
  const int l16 = lane & 15;
  const int wm = (wave >> 1) * 64;
  const int wn = (wave & 1) * 64;
  const int srow = lane >> 3;                       // 0..7 within the 8-row chunk
  const int schunk = ((lane & 7) - srow) & 7;       // logical 16B chunk (swizzle src)

  f32x4 acc[4][4] = {};
  for (int kt = 0; kt < Kd; kt += 64) {
#pragma unroll
    for (int i = 0; i < 4; i++) {
      const int r = wave * 32 + i * 8;              // r % 8 == 0
      __builtin_amdgcn_global_load_lds(
          GLOBAL_AS(&A[(size_t)(m0 + r + srow) * Kd + kt + schunk * 8]),
          LDS_AS(&As[r][0]), 16, 0, 0);
      __builtin_amdgcn_global_load_lds(
          GLOBAL_AS(&W[(size_t)(n0 + r + srow) * Kd + kt + schunk * 8]),
          LDS_AS(&Bs[r][0]), 16, 0, 0);
    }
    __syncthreads();
#pragma unroll
    for (int ks = 0; ks < 2; ks++) {
      const int col = (((ks * 4 + quad + l16) & 7)) * 8;   // swizzled read chunk
      bf16x8 af[4], bfr[4];
#pragma unroll
      for (int t = 0; t < 4; t++)
        af[t] = *reinterpret_cast<const bf16x8*>(&As[wm + t * 16 + l16][col]);
#pragma unroll
      for (int t = 0; t < 4; t++)
        bfr[t] = *reinterpret_cast<const bf16x8*>(&Bs[wn + t * 16 + l16][col]);
#pragma unroll
      for (int tm = 0; tm < 4; tm++)
#pragma unroll
        for (int tn = 0; tn < 4; tn++)
          acc[tm][tn] = __builtin_amdgcn_mfma_f32_16x16x32_bf16(af[tm], bfr[tn], acc[tm][tn], 0, 0, 0);
    }
    __syncthreads();
  }
#pragma unroll
  for (int tm = 0; tm < 4; tm++) {
#pragma unroll
    for (int tn = 0; tn < 4; tn++) {
      const int row0 = m0 + wm + tm * 16 + quad * 4;
      if constexpr (MODE == MODE_OUT) {
        const int col = n0 + wn + tn * 16 + l16;
#pragma unroll
        for (int j = 0; j < 4; j++)
          Oout[(size_t)(row0 + j) * DMODEL + col] = acc[tm][tn][j];
      } else {
        const int mat = n0 >> 11;              // 0=Q 1=K 2=V
        const int col = (n0 & 2047) + wn + tn * 16 + l16;
        const int h = col >> 7, dd = col & 127;
        if (mat == 2) {
          const int b = row0 >> 11, s = row0 & 2047;
          bf16x4 pk;
#pragma unroll
          for (int j = 0; j < 4; j++) pk[j] = (bf16)acc[tm][tn][j];
          *reinterpret_cast<bf16x4*>(&Ov[((size_t)(b * NH + h) * HD + dd) * SEQ + s]) = pk;
        } else {
          bf16* O = mat ? Ok : Oq;
          const float scale = mat ? 1.0f : 0.08838834764831845f;
#pragma unroll
          for (int j = 0; j < 4; j++) {
            const int row = row0 + j;
            const int b = row >> 11, s = row & 2047;
            O[((size_t)(b * NH + h) * SEQ + s) * HD + dd] = (bf16)(acc[tm][tn][j] * scale);
          }
        }
      }
    }
  }
}

// ---------------- flash attention, register-prefetch double-buffered ----------------
// Triangle-folded (block does qt=j and qt=31-j: 33 key-tiles, perfectly balanced),
// grid (16,32)=512 blocks, LDS padded to force exactly 2 blocks/CU.
// Tile t+1 is loaded into VGPRs (kpre/vpre) DURING tile t's compute; barriers only
// separate LDS write->read, so HBM latency is overlapped, never drained at a barrier.
// Physical LDS layout identical to round 6 (rotation swizzle, measured 0 conflicts).
__global__ __launch_bounds__(256, 2) void attn_kernel(
    const bf16* __restrict__ Q, const bf16* __restrict__ K,
    const bf16* __restrict__ Vt, bf16* __restrict__ Y) {
  const int j = blockIdx.x;          // 0..15
  const int bh = blockIdx.y;
  __shared__ __align__(16) char smem[54528];
  auto Ks  = (bf16(*)[128])smem;               // [64][128]  16384 B (swizzled)
  auto Vts = (bf16(*)[64])(smem + 16384);      // [128][64]  16384 B (swizzled)
  auto Ps  = (bf16(*)[16][72])(smem + 32768);  // [4][16][72] 9216 B (padded)
  // bytes 41984..54528: dead filler pinning occupancy at exactly 2 blocks/CU
  const int tid = threadIdx.x;
  const int wave = tid >> 6;
  const int lane = tid & 63;
  const int quad = lane >> 4;
  const int l16 = lane & 15;

  const bf16* Kbh = K + (size_t)bh * SEQ * HD;
  const bf16* Vbh = Vt + (size_t)bh * HD * SEQ;
  const int b = bh >> 4, h = bh & 15;

  // staging coords (identical physical layout to round 6 glds version)
  const int krow = lane >> 4;                     // 0..3
  const int kphys = lane & 15;
  const int vrow = lane >> 3;                     // 0..7
  const int vphys = lane & 7;
  const int vchunk = (vphys - vrow) & 7;          // i-invariant logical chunk
  // per-thread source offsets (kt-invariant)
  int koff[4], voff[4];
#pragma unroll
  for (int i = 0; i < 4; i++) {
    koff[i] = (wave * 16 + i * 4 + krow) * HD + (((kphys - krow - i * 4) & 15) * 8);
    voff[i] = (wave * 32 + i * 8 + vrow) * SEQ + vchunk * 8;
  }

  for (int pass = 0; pass < 2; ++pass) {
    const int qt = pass ? (31 - j) : j;
    const int q0 = qt * 64;
    const int ntiles = qt + 1;

    // Q fragments (B-operand) in registers; q = wave*16 + l16
    const bf16* Qw = Q + ((size_t)bh * SEQ + q0 + wave * 16) * HD;
    bf16x8 qf[4];
#pragma unroll
    for (int kk = 0; kk < 4; kk++)
      qf[kk] = *reinterpret_cast<const bf16x8*>(&Qw[(size_t)l16 * HD + kk * 32 + quad * 8]);

    f32x4 oacc[8] = {};
    float m_i = -3.0e38f, l_i = 0.f;

    // prologue: prefetch tile 0 into registers
    uint4 kpre[4], vpre[4];
#pragma unroll
    for (int i = 0; i < 4; i++) {
      kpre[i] = *reinterpret_cast<const uint4*>(&Kbh[koff[i]]);
      vpre[i] = *reinterpret_cast<const uint4*>(&Vbh[voff[i]]);
    }

    for (int t = 0; t < ntiles; ++t) {
      __syncthreads();   // all waves done reading LDS tile t-1
      // ---- regs -> LDS (swizzled physical layout) ----
#pragma unroll
      for (int i = 0; i < 4; i++) {
        *reinterpret_cast<uint4*>(&Ks[wave * 16 + i * 4 + krow][kphys * 8]) = kpre[i];
        *reinterpret_cast<uint4*>(&Vts[wave * 32 + i * 8 + vrow][vphys * 8]) = vpre[i];
      }
      __syncthreads();   // tile t visible to all waves

      // ---- prefetch tile t+1 (overlaps with all compute below) ----
      if (t + 1 < ntiles) {
        const int ktn = (t + 1) * 64;
#pragma unroll
        for (int i = 0; i < 4; i++) {
          kpre[i] = *reinterpret_cast<const uint4*>(&Kbh[(size_t)ktn * HD + koff[i]]);
          vpre[i] = *reinterpret_cast<const uint4*>(&Vbh[ktn + voff[i]]);
        }
      }

      // ---- S^T = K Q^T ; swizzled Ks read: chunk (kk*4+quad+l16)&15 ----
      f32x4 sacc[4] = {};
#pragma unroll
      for (int kk = 0; kk < 4; kk++) {
        const int kcol = (((kk * 4 + quad + l16) & 15)) * 8;
        bf16x8 ka[4];
#pragma unroll
        for (int mt = 0; mt < 4; mt++)
          ka[mt] = *reinterpret_cast<const bf16x8*>(&Ks[mt * 16 + l16][kcol]);
#pragma unroll
        for (int mt = 0; mt < 4; mt++)
          sacc[mt] = __builtin_amdgcn_mfma_f32_16x16x32_bf16(ka[mt], qf[kk], sacc[mt], 0, 0, 0);
      }

      // ---- online softmax; lane's column = q = wave*16 + l16 ----
      const int qg_loc = wave * 16 + l16;
      float mx = -3.0e38f;
      if (t == ntiles - 1) {   // diagonal tile: causal mask (block-uniform branch)
#pragma unroll
        for (int mt = 0; mt < 4; mt++)
#pragma unroll
          for (int jj = 0; jj < 4; jj++) {
            const int kg = mt * 16 + quad * 4 + jj;
            float v = (kg <= qg_loc) ? sacc[mt][jj] : -3.0e38f;
            sacc[mt][jj] = v;
            mx = fmaxf(mx, v);
          }
      } else {
#pragma unroll
        for (int mt = 0; mt < 4; mt++)
#pragma unroll
          for (int jj = 0; jj < 4; jj++) mx = fmaxf(mx, sacc[mt][jj]);
      }
      mx = fmaxf(mx, __shfl_xor(mx, 16));
      mx = fmaxf(mx, __shfl_xor(mx, 32));
      const float mnew = fmaxf(m_i, mx);
      const float alpha = __expf(m_i - mnew);
      m_i = mnew;
      float rs = 0.f;
#pragma unroll
      for (int mt = 0; mt < 4; mt++)
#pragma unroll
        for (int jj = 0; jj < 4; jj++) {
          float p = __expf(sacc[mt][jj] - mnew);
          sacc[mt][jj] = p;
          rs += p;
        }
      rs += __shfl_xor(rs, 16);
      rs += __shfl_xor(rs, 32);
      l_i = l_i * alpha + rs;
#pragma unroll
      for (int mt8 = 0; mt8 < 8; mt8++)
#pragma unroll
        for (int jj = 0; jj < 4; jj++) oacc[mt8][jj] *= alpha;

      // ---- P^T -> per-wave padded LDS (B-operand layout Ps[q][key]) ----
#pragma unroll
      for (int mt = 0; mt < 4; mt++) {
        bf16x4 pk;
#pragma unroll
        for (int jj = 0; jj < 4; jj++) pk[jj] = (bf16)sacc[mt][jj];
        *reinterpret_cast<bf16x4*>(&Ps[wave][l16][mt * 16 + quad * 4]) = pk;
      }

      // ---- O^T += V^T P^T ; swizzled Vts read ----
#pragma unroll
      for (int kk2 = 0; kk2 < 2; kk2++) {
        const int vcol = ((kk2 * 4 + quad + l16) & 7) * 8;
        bf16x8 pb = *reinterpret_cast<const bf16x8*>(&Ps[wave][l16][kk2 * 32 + quad * 8]);
#pragma unroll
        for (int mt8 = 0; mt8 < 8; mt8++) {
          bf16x8 av = *reinterpret_cast<const bf16x8*>(&Vts[mt8 * 16 + l16][vcol]);
          oacc[mt8] = __builtin_amdgcn_mfma_f32_16x16x32_bf16(av, pb, oacc[mt8], 0, 0, 0);
        }
      }
    }

    // ---- epilogue: O^T/l -> Y[b][s][h*128+d] ----
    const float inv = 1.0f / l_i;
    const int qg = q0 + wave * 16 + l16;
#pragma unroll
    for (int mt8 = 0; mt8 < 8; mt8++) {
      bf16x4 pk;
#pragma unroll
      for (int jj = 0; jj < 4; jj++) pk[jj] = (bf16)(oacc[mt8][jj] * inv);
      *reinterpret_cast<bf16x4*>(
          &Y[(size_t)(b * SEQ + qg) * DMODEL + h * HD + mt8 * 16 + quad * 4]) = pk;
    }
  }
}

// ---------------- launch ----------------
extern "C" void kernel_launch(void* const* d_in, const int* in_sizes, int n_in,
                              void* d_out, int out_size, void* d_ws, size_t ws_size,
                              hipStream_t stream) {
  const float* x  = (const float*)d_in[0];
  const float* Wq = (const float*)d_in[2];
  const float* Wk = (const float*)d_in[3];
  const float* Wv = (const float*)d_in[4];
  const float* Wo = (const float*)d_in[5];
  float* out = (float*)d_out;

  char* ws = (char*)d_ws;
  bf16* xb  = (bf16*)(ws + 0);
  bf16* Wqb = (bf16*)(ws + 16777216);    // Wq,Wk,Wv contiguous -> one [6144][2048]
  bf16* Wob = (bf16*)(ws + 41943040);
  bf16* Qb  = (bf16*)(ws + 50331648);    // [B,H,S,d]
  bf16* Kb  = (bf16*)(ws + 67108864);    // [B,H,S,d]
  bf16* Vtb = (bf16*)(ws + 83886080);    // [B,H,d,S]
  bf16* Yb  = xb;                        // [B,S,D] (x dead after projections)
  if (ws_size < 100663296) return;

  // one fused convert: 6,291,456 float4 groups -> 24576 blocks
  cvt5_kernel<<<24576, 256, 0, stream>>>(x, Wq, Wk, Wv, Wo, xb);

  gemm_bt<MODE_QKV><<<dim3(48, MROWS / 128), 256, 0, stream>>>(
      xb, Wqb, Qb, Kb, Vtb, nullptr);

  attn_kernel<<<dim3(16, BATCH * NH), 256, 0, stream>>>(Qb, Kb, Vtb, Yb);

  gemm_bt<MODE_OUT><<<dim3(16, MROWS / 128), 256, 0, stream>>>(
      Yb, Wob, nullptr, nullptr, nullptr, out);
}

// Round 9
// 368.536 us; speedup vs baseline: 1.2514x; 1.2514x over previous
//
#include <hip/hip_runtime.h>
#include <hip/hip_bf16.h>
#include <cstdint>
#include <cstddef>

typedef __bf16 bf16;
typedef __bf16 bf16x8 __attribute__((ext_vector_type(8)));
typedef __bf16 bf16x4 __attribute__((ext_vector_type(4)));
typedef float f32x4 __attribute__((ext_vector_type(4)));

static constexpr int BATCH = 2;
static constexpr int SEQ = 2048;
static constexpr int DMODEL = 2048;
static constexpr int NH = 16;
static constexpr int HD = 128;
static constexpr int MROWS = BATCH * SEQ; // 4096

#define GLOBAL_AS(p) ((const __attribute__((address_space(1))) void*)(p))
#define LDS_AS(p)    ((__attribute__((address_space(3))) void*)(p))
// wait vmcnt(0) only (expcnt=7, lgkmcnt=15 = no-wait): drains this wave's
// outstanding global_load_lds BEFORE s_barrier so other waves may read its rows.
#define WAIT_VMCNT0() __builtin_amdgcn_s_waitcnt(0x0F70)

// ---------------- fused fp32 -> bf16 convert (x, Wq, Wk, Wv, Wo in one launch) ----
__global__ void cvt5_kernel(const float* __restrict__ x,
                            const float* __restrict__ wq, const float* __restrict__ wk,
                            const float* __restrict__ wv, const float* __restrict__ wo,
                            bf16* __restrict__ dst) {
  const int i = blockIdx.x * blockDim.x + threadIdx.x;   // global float4 index
  const float* src;
  int local;
  if (i < 2097152) { src = x; local = i; }
  else {
    const int r = i - 2097152;
    const int w = r >> 20;            // 0..3 (block-uniform: 4096 blocks per weight)
    local = r & 1048575;
    src = (w == 0) ? wq : (w == 1) ? wk : (w == 2) ? wv : wo;
  }
  float4 f = reinterpret_cast<const float4*>(src)[local];
  bf16x4 o;
  o.x = (bf16)f.x; o.y = (bf16)f.y; o.z = (bf16)f.z; o.w = (bf16)f.w;
  reinterpret_cast<bf16x4*>(dst)[i] = o;
}

// ---------------- GEMM: C = A(MxK,row) * W(NxK,row)^T ----------------
// m97 structure + rotation swizzle (round 6: 0 bank conflicts, ~1000 TF).
enum { MODE_QKV = 0, MODE_OUT = 1 };

template <int MODE>
__global__ __launch_bounds__(256, 4) void gemm_bt(
    const bf16* __restrict__ A, const bf16* __restrict__ W,
    bf16* __restrict__ Oq, bf16* __restrict__ Ok, bf16* __restrict__ Ov,
    float* __restrict__ Oout) {
  constexpr int Kd = DMODEL;
  __shared__ __align__(16) bf16 As[128][64];
  __shared__ __align__(16) bf16 Bs[128][64];
  const int n0 = blockIdx.x * 128;
  const int m0 = blockIdx.y * 128;
  const int tid = threadIdx.x;
  const int wave = tid >> 6;
  const int lane = tid & 63;
  const int quad = lane >> 4;
  const int l16 = lane & 15;
  const int wm = (wave >> 1) * 64;
  const int wn = (wave & 1) * 64;
  const int srow = lane >> 3;                       // 0..7 within the 8-row chunk
  const int schunk = ((lane & 7) - srow) & 7;       // logical 16B chunk (swizzle src)

  f32x4 acc[4][4] = {};
  for (int kt = 0; kt < Kd; kt += 64) {
#pragma unroll
    for (int i = 0; i < 4; i++) {
      const int r = wave * 32 + i * 8;              // r % 8 == 0
      __builtin_amdgcn_global_load_lds(
          GLOBAL_AS(&A[(size_t)(m0 + r + srow) * Kd + kt + schunk * 8]),
          LDS_AS(&As[r][0]), 16, 0, 0);
      __builtin_amdgcn_global_load_lds(
          GLOBAL_AS(&W[(size_t)(n0 + r + srow) * Kd + kt + schunk * 8]),
          LDS_AS(&Bs[r][0]), 16, 0, 0);
    }
    WAIT_VMCNT0();
    __syncthreads();
#pragma unroll
    for (int ks = 0; ks < 2; ks++) {
      const int col = (((ks * 4 + quad + l16) & 7)) * 8;   // swizzled read chunk
      bf16x8 af[4], bfr[4];
#pragma unroll
      for (int t = 0; t < 4; t++)
        af[t] = *reinterpret_cast<const bf16x8*>(&As[wm + t * 16 + l16][col]);
#pragma unroll
      for (int t = 0; t < 4; t++)
        bfr[t] = *reinterpret_cast<const bf16x8*>(&Bs[wn + t * 16 + l16][col]);
#pragma unroll
      for (int tm = 0; tm < 4; tm++)
#pragma unroll
        for (int tn = 0; tn < 4; tn++)
          acc[tm][tn] = __builtin_amdgcn_mfma_f32_16x16x32_bf16(af[tm], bfr[tn], acc[tm][tn], 0, 0, 0);
    }
    __syncthreads();
  }
#pragma unroll
  for (int tm = 0; tm < 4; tm++) {
#pragma unroll
    for (int tn = 0; tn < 4; tn++) {
      const int row0 = m0 + wm + tm * 16 + quad * 4;
      if constexpr (MODE == MODE_OUT) {
        const int col = n0 + wn + tn * 16 + l16;
#pragma unroll
        for (int j = 0; j < 4; j++)
          Oout[(size_t)(row0 + j) * DMODEL + col] = acc[tm][tn][j];
      } else {
        const int mat = n0 >> 11;              // 0=Q 1=K 2=V
        const int col = (n0 & 2047) + wn + tn * 16 + l16;
        const int h = col >> 7, dd = col & 127;
        if (mat == 2) {
          const int b = row0 >> 11, s = row0 & 2047;
          bf16x4 pk;
#pragma unroll
          for (int j = 0; j < 4; j++) pk[j] = (bf16)acc[tm][tn][j];
          *reinterpret_cast<bf16x4*>(&Ov[((size_t)(b * NH + h) * HD + dd) * SEQ + s]) = pk;
        } else {
          bf16* O = mat ? Ok : Oq;
          const float scale = mat ? 1.0f : 0.08838834764831845f;
#pragma unroll
          for (int j = 0; j < 4; j++) {
            const int row = row0 + j;
            const int b = row >> 11, s = row & 2047;
            O[((size_t)(b * NH + h) * SEQ + s) * HD + dd] = (bf16)(acc[tm][tn][j] * scale);
          }
        }
      }
    }
  }
}

// ---------------- flash attention, K-double-buffered glds pipeline ----------------
// Round 8 + explicit pre-barrier vmcnt(0) drains. Round 8's failure mechanism:
// with cross-iteration glds consumption, the compiler placed each wave's vmcnt
// wait AFTER the barrier (before its own first ds_read) — correct same-wave,
// racy cross-wave (wave A reads wave B's staged rows before B's glds lands).
// WAIT_VMCNT0 before each barrier enforces drain-before-barrier semantics.
__global__ __launch_bounds__(256, 2) void attn_kernel(
    const bf16* __restrict__ Q, const bf16* __restrict__ K,
    const bf16* __restrict__ Vt, bf16* __restrict__ Y) {
  const int j = blockIdx.x;          // 0..15
  const int bh = blockIdx.y;
  __shared__ __align__(16) char smem[58368];
  auto Ks  = (bf16(*)[64][128])smem;           // [2][64][128] 32768 B (swizzled)
  auto Vts = (bf16(*)[64])(smem + 32768);      // [128][64]    16384 B (swizzled)
  auto Ps  = (bf16(*)[16][72])(smem + 49152);  // [4][16][72]   9216 B (padded)
  const int tid = threadIdx.x;
  const int wave = tid >> 6;
  const int lane = tid & 63;
  const int quad = lane >> 4;
  const int l16 = lane & 15;

  const bf16* Kbh = K + (size_t)bh * SEQ * HD;
  const bf16* Vbh = Vt + (size_t)bh * HD * SEQ;
  const int b = bh >> 4, h = bh & 15;

  // staging coords (rotation swizzle, same physical layout as round 6)
  const int krow = lane >> 4;                     // 0..3
  const int kphys = lane & 15;
  const int vrow = lane >> 3;                     // 0..7
  const int vphys = lane & 7;
  const int vchunk = (vphys - vrow) & 7;          // i-invariant logical chunk

  for (int pass = 0; pass < 2; ++pass) {
    const int qt = pass ? (31 - j) : j;
    const int q0 = qt * 64;
    const int ntiles = qt + 1;

    // Q fragments (B-operand) in registers; q = wave*16 + l16
    const bf16* Qw = Q + ((size_t)bh * SEQ + q0 + wave * 16) * HD;
    bf16x8 qf[4];
#pragma unroll
    for (int kk = 0; kk < 4; kk++)
      qf[kk] = *reinterpret_cast<const bf16x8*>(&Qw[(size_t)l16 * HD + kk * 32 + quad * 8]);

    f32x4 oacc[8] = {};
    float m_i = -3.0e38f, l_i = 0.f;

    __syncthreads();   // previous pass done with all LDS before prestage
    // prestage K(0) -> Ks[0]
#pragma unroll
    for (int i = 0; i < 4; i++) {
      const int rbase = wave * 16 + i * 4;
      const int c = ((kphys - krow - i * 4) & 15);
      __builtin_amdgcn_global_load_lds(
          GLOBAL_AS(&Kbh[(size_t)(rbase + krow) * HD + c * 8]),
          LDS_AS(&Ks[0][rbase][0]), 16, 0, 0);
    }

    for (int t = 0; t < ntiles; ++t) {
      const int kt = t * 64;
      const int X = t & 1;
      WAIT_VMCNT0();     // drain this wave's K(t) glds BEFORE the barrier
      __syncthreads();   // (a): K(t) in LDS, all waves; Vts/Ps reads of t-1 done

      // ---- issue V(t) glds (drained before (b), hidden by S^T+softmax) ----
#pragma unroll
      for (int i = 0; i < 4; i++) {
        const int rbase = wave * 32 + i * 8;
        __builtin_amdgcn_global_load_lds(
            GLOBAL_AS(&Vbh[(size_t)(rbase + vrow) * SEQ + kt + vchunk * 8]),
            LDS_AS(&Vts[rbase][0]), 16, 0, 0);
      }

      // ---- S^T = K Q^T from Ks[X] ; swizzled read: chunk (kk*4+quad+l16)&15 ----
      f32x4 sacc[4] = {};
#pragma unroll
      for (int kk = 0; kk < 4; kk++) {
        const int kcol = (((kk * 4 + quad + l16) & 15)) * 8;
        bf16x8 ka[4];
#pragma unroll
        for (int mt = 0; mt < 4; mt++)
          ka[mt] = *reinterpret_cast<const bf16x8*>(&Ks[X][mt * 16 + l16][kcol]);
#pragma unroll
        for (int mt = 0; mt < 4; mt++)
          sacc[mt] = __builtin_amdgcn_mfma_f32_16x16x32_bf16(ka[mt], qf[kk], sacc[mt], 0, 0, 0);
      }

      // ---- online softmax; lane's column = q = wave*16 + l16 ----
      const int qg_loc = wave * 16 + l16;
      float mx = -3.0e38f;
      if (t == ntiles - 1) {   // diagonal tile: causal mask (block-uniform branch)
#pragma unroll
        for (int mt = 0; mt < 4; mt++)
#pragma unroll
          for (int jj = 0; jj < 4; jj++) {
            const int kg = mt * 16 + quad * 4 + jj;
            float v = (kg <= qg_loc) ? sacc[mt][jj] : -3.0e38f;
            sacc[mt][jj] = v;
            mx = fmaxf(mx, v);
          }
      } else {
#pragma unroll
        for (int mt = 0; mt < 4; mt++)
#pragma unroll
          for (int jj = 0; jj < 4; jj++) mx = fmaxf(mx, sacc[mt][jj]);
      }
      mx = fmaxf(mx, __shfl_xor(mx, 16));
      mx = fmaxf(mx, __shfl_xor(mx, 32));
      const float mnew = fmaxf(m_i, mx);
      const float alpha = __expf(m_i - mnew);
      m_i = mnew;
      float rs = 0.f;
#pragma unroll
      for (int mt = 0; mt < 4; mt++)
#pragma unroll
        for (int jj = 0; jj < 4; jj++) {
          float p = __expf(sacc[mt][jj] - mnew);
          sacc[mt][jj] = p;
          rs += p;
        }
      rs += __shfl_xor(rs, 16);
      rs += __shfl_xor(rs, 32);
      l_i = l_i * alpha + rs;
#pragma unroll
      for (int mt8 = 0; mt8 < 8; mt8++)
#pragma unroll
        for (int jj = 0; jj < 4; jj++) oacc[mt8][jj] *= alpha;

      // ---- P^T -> per-wave padded LDS (B-operand layout Ps[q][key]) ----
#pragma unroll
      for (int mt = 0; mt < 4; mt++) {
        bf16x4 pk;
#pragma unroll
        for (int jj = 0; jj < 4; jj++) pk[jj] = (bf16)sacc[mt][jj];
        *reinterpret_cast<bf16x4*>(&Ps[wave][l16][mt * 16 + quad * 4]) = pk;
      }

      WAIT_VMCNT0();     // drain this wave's V(t) glds BEFORE the barrier
      __syncthreads();   // (b): Vts(t) in LDS, all waves

      // ---- issue K(t+1) glds into other buffer (drained before next (a)) ----
      if (t + 1 < ntiles) {
        const int ktn = kt + 64;
#pragma unroll
        for (int i = 0; i < 4; i++) {
          const int rbase = wave * 16 + i * 4;
          const int c = ((kphys - krow - i * 4) & 15);
          __builtin_amdgcn_global_load_lds(
              GLOBAL_AS(&Kbh[(size_t)(ktn + rbase + krow) * HD + c * 8]),
              LDS_AS(&Ks[1 - X][rbase][0]), 16, 0, 0);
        }
      }

      // ---- O^T += V^T P^T ; swizzled Vts read ----
#pragma unroll
      for (int kk2 = 0; kk2 < 2; kk2++) {
        const int vcol = ((kk2 * 4 + quad + l16) & 7) * 8;
        bf16x8 pb = *reinterpret_cast<const bf16x8*>(&Ps[wave][l16][kk2 * 32 + quad * 8]);
#pragma unroll
        for (int mt8 = 0; mt8 < 8; mt8++) {
          bf16x8 av = *reinterpret_cast<const bf16x8*>(&Vts[mt8 * 16 + l16][vcol]);
          oacc[mt8] = __builtin_amdgcn_mfma_f32_16x16x32_bf16(av, pb, oacc[mt8], 0, 0, 0);
        }
      }
    }

    // ---- epilogue: O^T/l -> Y[b][s][h*128+d] ----
    const float inv = 1.0f / l_i;
    const int qg = q0 + wave * 16 + l16;
#pragma unroll
    for (int mt8 = 0; mt8 < 8; mt8++) {
      bf16x4 pk;
#pragma unroll
      for (int jj = 0; jj < 4; jj++) pk[jj] = (bf16)(oacc[mt8][jj] * inv);
      *reinterpret_cast<bf16x4*>(
          &Y[(size_t)(b * SEQ + qg) * DMODEL + h * HD + mt8 * 16 + quad * 4]) = pk;
    }
  }
}

// ---------------- launch ----------------
extern "C" void kernel_launch(void* const* d_in, const int* in_sizes, int n_in,
                              void* d_out, int out_size, void* d_ws, size_t ws_size,
                              hipStream_t stream) {
  const float* x  = (const float*)d_in[0];
  const float* Wq = (const float*)d_in[2];
  const float* Wk = (const float*)d_in[3];
  const float* Wv = (const float*)d_in[4];
  const float* Wo = (const float*)d_in[5];
  float* out = (float*)d_out;

  char* ws = (char*)d_ws;
  bf16* xb  = (bf16*)(ws + 0);
  bf16* Wqb = (bf16*)(ws + 16777216);    // Wq,Wk,Wv contiguous -> one [6144][2048]
  bf16* Wob = (bf16*)(ws + 41943040);
  bf16* Qb  = (bf16*)(ws + 50331648);    // [B,H,S,d]
  bf16* Kb  = (bf16*)(ws + 67108864);    // [B,H,S,d]
  bf16* Vtb = (bf16*)(ws + 83886080);    // [B,H,d,S]
  bf16* Yb  = xb;                        // [B,S,D] (x dead after projections)
  if (ws_size < 100663296) return;

  // one fused convert: 6,291,456 float4 groups -> 24576 blocks
  cvt5_kernel<<<24576, 256, 0, stream>>>(x, Wq, Wk, Wv, Wo, xb);

  gemm_bt<MODE_QKV><<<dim3(48, MROWS / 128), 256, 0, stream>>>(
      xb, Wqb, Qb, Kb, Vtb, nullptr);

  attn_kernel<<<dim3(16, BATCH * NH), 256, 0, stream>>>(Qb, Kb, Vtb, Yb);

  gemm_bt<MODE_OUT><<<dim3(16, MROWS / 128), 256, 0, stream>>>(
      Yb, Wob, nullptr, nullptr, nullptr, out);
}

// Round 10
// 366.031 us; speedup vs baseline: 1.2600x; 1.0068x over previous
//
#include <hip/hip_runtime.h>
#include <hip/hip_bf16.h>
#include <cstdint>
#include <cstddef>

typedef __bf16 bf16;
typedef __bf16 bf16x8 __attribute__((ext_vector_type(8)));
typedef __bf16 bf16x4 __attribute__((ext_vector_type(4)));
typedef float f32x4 __attribute__((ext_vector_type(4)));

static constexpr int BATCH = 2;
static constexpr int SEQ = 2048;
static constexpr int DMODEL = 2048;
static constexpr int NH = 16;
static constexpr int HD = 128;
static constexpr int MROWS = BATCH * SEQ; // 4096

#define GLOBAL_AS(p) ((const __attribute__((address_space(1))) void*)(p))
#define LDS_AS(p)    ((__attribute__((address_space(3))) void*)(p))
// wait vmcnt(0) only (expcnt=7, lgkmcnt=15 = no-wait): drains this wave's
// global_load_lds BEFORE s_barrier so other waves may read its staged rows.
#define WAIT_VMCNT0() __builtin_amdgcn_s_waitcnt(0x0F70)

// ---------------- fused fp32 -> bf16 convert ----------------
__global__ void cvt5_kernel(const float* __restrict__ x,
                            const float* __restrict__ wq, const float* __restrict__ wk,
                            const float* __restrict__ wv, const float* __restrict__ wo,
                            bf16* __restrict__ dst) {
  const int i = blockIdx.x * blockDim.x + threadIdx.x;   // global float4 index
  const float* src;
  int local;
  if (i < 2097152) { src = x; local = i; }
  else {
    const int r = i - 2097152;
    const int w = r >> 20;            // 0..3 (block-uniform)
    local = r & 1048575;
    src = (w == 0) ? wq : (w == 1) ? wk : (w == 2) ? wv : wo;
  }
  float4 f = reinterpret_cast<const float4*>(src)[local];
  bf16x4 o;
  o.x = (bf16)f.x; o.y = (bf16)f.y; o.z = (bf16)f.z; o.w = (bf16)f.w;
  reinterpret_cast<bf16x4*>(dst)[i] = o;
}

// ---------------- GEMM: C = A(MxK,row) * W(NxK,row)^T ----------------
// m97 structure + rotation swizzle (rounds 6/9: 0 bank conflicts, ~1000 TF).
enum { MODE_QKV = 0, MODE_OUT = 1 };

template <int MODE>
__global__ __launch_bounds__(256, 4) void gemm_bt(
    const bf16* __restrict__ A, const bf16* __restrict__ W,
    bf16* __restrict__ Oq, bf16* __restrict__ Ok, bf16* __restrict__ Ov,
    float* __restrict__ Oout) {
  constexpr int Kd = DMODEL;
  __shared__ __align__(16) bf16 As[128][64];
  __shared__ __align__(16) bf16 Bs[128][64];
  const int n0 = blockIdx.x * 128;
  const int m0 = blockIdx.y * 128;
  const int tid = threadIdx.x;
  const int wave = tid >> 6;
  const int lane = tid & 63;
  const int quad = lane >> 4;
  const int l16 = lane & 15;
  const int wm = (wave >> 1) * 64;
  const int wn = (wave & 1) * 64;
  const int srow = lane >> 3;
  const int schunk = ((lane & 7) - srow) & 7;

  f32x4 acc[4][4] = {};
  for (int kt = 0; kt < Kd; kt += 64) {
#pragma unroll
    for (int i = 0; i < 4; i++) {
      const int r = wave * 32 + i * 8;
      __builtin_amdgcn_global_load_lds(
          GLOBAL_AS(&A[(size_t)(m0 + r + srow) * Kd + kt + schunk * 8]),
          LDS_AS(&As[r][0]), 16, 0, 0);
      __builtin_amdgcn_global_load_lds(
          GLOBAL_AS(&W[(size_t)(n0 + r + srow) * Kd + kt + schunk * 8]),
          LDS_AS(&Bs[r][0]), 16, 0, 0);
    }
    WAIT_VMCNT0();
    __syncthreads();
#pragma unroll
    for (int ks = 0; ks < 2; ks++) {
      const int col = (((ks * 4 + quad + l16) & 7)) * 8;
      bf16x8 af[4], bfr[4];
#pragma unroll
      for (int t = 0; t < 4; t++)
        af[t] = *reinterpret_cast<const bf16x8*>(&As[wm + t * 16 + l16][col]);
#pragma unroll
      for (int t = 0; t < 4; t++)
        bfr[t] = *reinterpret_cast<const bf16x8*>(&Bs[wn + t * 16 + l16][col]);
#pragma unroll
      for (int tm = 0; tm < 4; tm++)
#pragma unroll
        for (int tn = 0; tn < 4; tn++)
          acc[tm][tn] = __builtin_amdgcn_mfma_f32_16x16x32_bf16(af[tm], bfr[tn], acc[tm][tn], 0, 0, 0);
    }
    __syncthreads();
  }
#pragma unroll
  for (int tm = 0; tm < 4; tm++) {
#pragma unroll
    for (int tn = 0; tn < 4; tn++) {
      const int row0 = m0 + wm + tm * 16 + quad * 4;
      if constexpr (MODE == MODE_OUT) {
        const int col = n0 + wn + tn * 16 + l16;
#pragma unroll
        for (int j = 0; j < 4; j++)
          Oout[(size_t)(row0 + j) * DMODEL + col] = acc[tm][tn][j];
      } else {
        const int mat = n0 >> 11;              // 0=Q 1=K 2=V
        const int col = (n0 & 2047) + wn + tn * 16 + l16;
        const int h = col >> 7, dd = col & 127;
        if (mat == 2) {
          const int b = row0 >> 11, s = row0 & 2047;
          bf16x4 pk;
#pragma unroll
          for (int j = 0; j < 4; j++) pk[j] = (bf16)acc[tm][tn][j];
          *reinterpret_cast<bf16x4*>(&Ov[((size_t)(b * NH + h) * HD + dd) * SEQ + s]) = pk;
        } else {
          bf16* O = mat ? Ok : Oq;
          const float scale = mat ? 1.0f : 0.08838834764831845f;
#pragma unroll
          for (int j = 0; j < 4; j++) {
            const int row = row0 + j;
            const int b = row >> 11, s = row & 2047;
            O[((size_t)(b * NH + h) * SEQ + s) * HD + dd] = (bf16)(acc[tm][tn][j] * scale);
          }
        }
      }
    }
  }
}

// ---------------- flash attention, nt=2 (32 q-rows/wave, 128-q-tile blocks) ----
// 256 blocks (grid 8x32), triangle-folded: qt=j and qt=15-j -> every block does
// exactly 34 key-tiles of 64. Halves tile-units/CU (66->34) and LDS reads/MFMA
// (ka/av reads feed both nt fragments). Round-9-proven K-dbuf pipeline with
// pre-barrier vmcnt(0) drains. LDS exactly 64 KB -> 1 block/CU (256 blocks).
// Ps uses a 16B rotation swizzle (phys chunk (c16+row)&7) instead of padding.
__global__ __launch_bounds__(256, 2) void attn_kernel(
    const bf16* __restrict__ Q, const bf16* __restrict__ K,
    const bf16* __restrict__ Vt, bf16* __restrict__ Y) {
  const int j = blockIdx.x;          // 0..7
  const int bh = blockIdx.y;
  __shared__ __align__(16) char smem[65536];
  auto Ks  = (bf16(*)[64][128])smem;           // [2][64][128] 32768 B (swizzled)
  auto Vts = (bf16(*)[64])(smem + 32768);      // [128][64]    16384 B (swizzled)
  char* PsW;                                   // per-wave 32x64 bf16, 16B-rot-swizzled
  const int tid = threadIdx.x;
  const int wave = tid >> 6;
  const int lane = tid & 63;
  const int quad = lane >> 4;
  const int l16 = lane & 15;
  PsW = smem + 49152 + wave * 4096;

  const bf16* Kbh = K + (size_t)bh * SEQ * HD;
  const bf16* Vbh = Vt + (size_t)bh * HD * SEQ;
  const int b = bh >> 4, h = bh & 15;

  // staging coords (rotation swizzle, physical layout proven 0-conflict)
  const int krow = lane >> 4;                     // 0..3
  const int kphys = lane & 15;
  const int vrow = lane >> 3;                     // 0..7
  const int vphys = lane & 7;
  const int vchunk = (vphys - vrow) & 7;

  for (int pass = 0; pass < 2; ++pass) {
    const int qt = pass ? (15 - j) : j;
    const int q0 = qt * 128;
    const int ntiles = 2 * qt + 2;

    // Q fragments (B-operand) in registers; q = q0 + wave*32 + nt*16 + l16
    const bf16* Qw = Q + ((size_t)bh * SEQ + q0 + wave * 32) * HD;
    bf16x8 qf[2][4];
#pragma unroll
    for (int nt = 0; nt < 2; nt++)
#pragma unroll
      for (int kk = 0; kk < 4; kk++)
        qf[nt][kk] = *reinterpret_cast<const bf16x8*>(
            &Qw[(size_t)(nt * 16 + l16) * HD + kk * 32 + quad * 8]);

    f32x4 oacc[8][2] = {};
    float m_i[2] = {-3.0e38f, -3.0e38f};
    float l_i[2] = {0.f, 0.f};

    __syncthreads();   // previous pass done with all LDS before prestage
    // prestage K(0) -> Ks[0]
#pragma unroll
    for (int i = 0; i < 4; i++) {
      const int rbase = wave * 16 + i * 4;
      const int c = ((kphys - krow - i * 4) & 15);
      __builtin_amdgcn_global_load_lds(
          GLOBAL_AS(&Kbh[(size_t)(rbase + krow) * HD + c * 8]),
          LDS_AS(&Ks[0][rbase][0]), 16, 0, 0);
    }

    for (int t = 0; t < ntiles; ++t) {
      const int kt = t * 64;
      const int X = t & 1;
      WAIT_VMCNT0();     // drain this wave's K(t) glds BEFORE the barrier
      __syncthreads();   // (a): K(t) visible; t-1's Vts/Ks reads complete

      // ---- issue V(t) glds (drained before (b), hidden by S^T+softmax) ----
#pragma unroll
      for (int i = 0; i < 4; i++) {
        const int rbase = wave * 32 + i * 8;
        __builtin_amdgcn_global_load_lds(
            GLOBAL_AS(&Vbh[(size_t)(rbase + vrow) * SEQ + kt + vchunk * 8]),
            LDS_AS(&Vts[rbase][0]), 16, 0, 0);
      }

      // ---- S^T = K Q^T from Ks[X] : ka shared across both nt ----
      f32x4 sacc[4][2] = {};
#pragma unroll
      for (int kk = 0; kk < 4; kk++) {
        const int kcol = (((kk * 4 + quad + l16) & 15)) * 8;
        bf16x8 ka[4];
#pragma unroll
        for (int mt = 0; mt < 4; mt++)
          ka[mt] = *reinterpret_cast<const bf16x8*>(&Ks[X][mt * 16 + l16][kcol]);
#pragma unroll
        for (int mt = 0; mt < 4; mt++)
#pragma unroll
          for (int nt = 0; nt < 2; nt++)
            sacc[mt][nt] = __builtin_amdgcn_mfma_f32_16x16x32_bf16(ka[mt], qf[nt][kk], sacc[mt][nt], 0, 0, 0);
      }

      // ---- online softmax per nt; lane's column = q = wave*32 + nt*16 + l16 ----
      const bool mask_tile = (t >= ntiles - 2);   // block-uniform
#pragma unroll
      for (int nt = 0; nt < 2; nt++) {
        const int qg = q0 + wave * 32 + nt * 16 + l16;
        float mx = -3.0e38f;
        if (mask_tile) {
#pragma unroll
          for (int mt = 0; mt < 4; mt++)
#pragma unroll
            for (int jj = 0; jj < 4; jj++) {
              const int kg = kt + mt * 16 + quad * 4 + jj;
              float v = (kg <= qg) ? sacc[mt][nt][jj] : -3.0e38f;
              sacc[mt][nt][jj] = v;
              mx = fmaxf(mx, v);
            }
        } else {
#pragma unroll
          for (int mt = 0; mt < 4; mt++)
#pragma unroll
            for (int jj = 0; jj < 4; jj++) mx = fmaxf(mx, sacc[mt][nt][jj]);
        }
        mx = fmaxf(mx, __shfl_xor(mx, 16));
        mx = fmaxf(mx, __shfl_xor(mx, 32));
        const float mnew = fmaxf(m_i[nt], mx);
        const float alpha = __expf(m_i[nt] - mnew);
        m_i[nt] = mnew;
        float rs = 0.f;
#pragma unroll
        for (int mt = 0; mt < 4; mt++)
#pragma unroll
          for (int jj = 0; jj < 4; jj++) {
            float p = __expf(sacc[mt][nt][jj] - mnew);
            sacc[mt][nt][jj] = p;
            rs += p;
          }
        rs += __shfl_xor(rs, 16);
        rs += __shfl_xor(rs, 32);
        l_i[nt] = l_i[nt] * alpha + rs;
#pragma unroll
        for (int mt8 = 0; mt8 < 8; mt8++)
#pragma unroll
          for (int jj = 0; jj < 4; jj++) oacc[mt8][nt][jj] *= alpha;

        // ---- P^T -> per-wave LDS, 16B rotation swizzle: row=nt*16+l16,
        //      logical c16 = mt*2+(quad>>1), phys = (c16+row)&7, +8B if quad odd
#pragma unroll
        for (int mt = 0; mt < 4; mt++) {
          bf16x4 pk;
#pragma unroll
          for (int jj = 0; jj < 4; jj++) pk[jj] = (bf16)sacc[mt][nt][jj];
          const int row = nt * 16 + l16;
          const int ph = (mt * 2 + (quad >> 1) + row) & 7;
          *reinterpret_cast<bf16x4*>(&PsW[row * 128 + ph * 16 + (quad & 1) * 8]) = pk;
        }
      }

      WAIT_VMCNT0();     // drain this wave's V(t) glds BEFORE the barrier
      __syncthreads();   // (b): Vts(t) visible to all waves

      // ---- issue K(t+1) glds into other buffer (drained before next (a)) ----
      if (t + 1 < ntiles) {
        const int ktn = kt + 64;
#pragma unroll
        for (int i = 0; i < 4; i++) {
          const int rbase = wave * 16 + i * 4;
          const int c = ((kphys - krow - i * 4) & 15);
          __builtin_amdgcn_global_load_lds(
              GLOBAL_AS(&Kbh[(size_t)(ktn + rbase + krow) * HD + c * 8]),
              LDS_AS(&Ks[1 - X][rbase][0]), 16, 0, 0);
        }
      }

      // ---- O^T += V^T P^T : av shared across both nt ----
#pragma unroll
      for (int kk2 = 0; kk2 < 2; kk2++) {
        bf16x8 pb[2];
#pragma unroll
        for (int nt = 0; nt < 2; nt++) {
          const int row = nt * 16 + l16;
          const int ph = (kk2 * 4 + quad + row) & 7;
          pb[nt] = *reinterpret_cast<const bf16x8*>(&PsW[row * 128 + ph * 16]);
        }
        const int vcol = ((kk2 * 4 + quad + l16) & 7) * 8;
#pragma unroll
        for (int mt8 = 0; mt8 < 8; mt8++) {
          bf16x8 av = *reinterpret_cast<const bf16x8*>(&Vts[mt8 * 16 + l16][vcol]);
#pragma unroll
          for (int nt = 0; nt < 2; nt++)
            oacc[mt8][nt] = __builtin_amdgcn_mfma_f32_16x16x32_bf16(av, pb[nt], oacc[mt8][nt], 0, 0, 0);
        }
      }
    }

    // ---- epilogue: O^T/l -> Y[b][s][h*128+d] ----
#pragma unroll
    for (int nt = 0; nt < 2; nt++) {
      const float inv = 1.0f / l_i[nt];
      const int qg = q0 + wave * 32 + nt * 16 + l16;
#pragma unroll
      for (int mt8 = 0; mt8 < 8; mt8++) {
        bf16x4 pk;
#pragma unroll
        for (int jj = 0; jj < 4; jj++) pk[jj] = (bf16)(oacc[mt8][nt][jj] * inv);
        *reinterpret_cast<bf16x4*>(
            &Y[(size_t)(b * SEQ + qg) * DMODEL + h * HD + mt8 * 16 + quad * 4]) = pk;
      }
    }
  }
}

// ---------------- launch ----------------
extern "C" void kernel_launch(void* const* d_in, const int* in_sizes, int n_in,
                              void* d_out, int out_size, void* d_ws, size_t ws_size,
                              hipStream_t stream) {
  const float* x  = (const float*)d_in[0];
  const float* Wq = (const float*)d_in[2];
  const float* Wk = (const float*)d_in[3];
  const float* Wv = (const float*)d_in[4];
  const float* Wo = (const float*)d_in[5];
  float* out = (float*)d_out;

  char* ws = (char*)d_ws;
  bf16* xb  = (bf16*)(ws + 0);
  bf16* Wqb = (bf16*)(ws + 16777216);    // Wq,Wk,Wv contiguous -> one [6144][2048]
  bf16* Wob = (bf16*)(ws + 41943040);
  bf16* Qb  = (bf16*)(ws + 50331648);    // [B,H,S,d]
  bf16* Kb  = (bf16*)(ws + 67108864);    // [B,H,S,d]
  bf16* Vtb = (bf16*)(ws + 83886080);    // [B,H,d,S]
  bf16* Yb  = xb;                        // [B,S,D] (x dead after projections)
  if (ws_size < 100663296) return;

  cvt5_kernel<<<24576, 256, 0, stream>>>(x, Wq, Wk, Wv, Wo, xb);

  gemm_bt<MODE_QKV><<<dim3(48, MROWS / 128), 256, 0, stream>>>(
      xb, Wqb, Qb, Kb, Vtb, nullptr);

  attn_kernel<<<dim3(8, BATCH * NH), 256, 0, stream>>>(Qb, Kb, Vtb, Yb);

  gemm_bt<MODE_OUT><<<dim3(16, MROWS / 128), 256, 0, stream>>>(
      Yb, Wob, nullptr, nullptr, nullptr, out);
}